// Round 1
// baseline (313.643 us; speedup 1.0000x reference)
//
#include <hip/hip_runtime.h>
#include <math.h>

#define NN 4096
#define ALPHA 0.1f
#define DT 0.01f
#define DIFF 10.0f
#define EPS 1e-9f
#define HB 1.5707963267948966f
#define CHUNK 1024

// Per-i staging struct (12 floats, 48B):
// [0] ci  [1] si  [2] axx(=ta*xi-tb*yi-xi)  [3] ayy(=tb*xi+ta*yi-yi)
// [4] xi  [5] yi  [6] xnlo [7] xnhi [8] ynlo [9] ynhi
// [10] up(=ci*xi+si*yi)  [11] vp(=si*xi-ci*yi)

__global__ void prep_kernel(const float* __restrict__ phase,
                            const float* __restrict__ w,
                            const float* __restrict__ ha,
                            const float* __restrict__ xy,
                            const float* __restrict__ xydo,
                            float* __restrict__ st,
                            float* __restrict__ upv) {
  int i = blockIdx.x * blockDim.x + threadIdx.x;
  if (i >= NN) return;
  float ph = phase[i];
  float ci = cosf(ph), si = sinf(ph);
  float2 p2 = reinterpret_cast<const float2*>(xy)[i];
  float xi = p2.x, yi = p2.y;
  float2 d2 = reinterpret_cast<const float2*>(xydo)[i];
  float xdo = d2.x, ydo = d2.y;
  float r2 = xi * xi + yi * yi;
  float ta = ALPHA * (1.0f - r2 * r2);
  float zeta = 1.0f - ha[i] * ((xdo + EPS) / (fabsf(xdo) + EPS));
  float tb = w[i] / (zeta + EPS);
  float* p = st + i * 12;
  p[0] = ci;
  p[1] = si;
  p[2] = ta * xi - tb * yi - xi;
  p[3] = tb * xi + ta * yi - yi;
  p[4] = xi;
  p[5] = yi;
  p[6] = fmaf(xdo - DIFF, DT, xi);
  p[7] = fmaf(xdo + DIFF, DT, xi);
  p[8] = fmaf(ydo - DIFF, DT, yi);
  p[9] = fmaf(ydo + DIFF, DT, yi);
  float up = ci * xi + si * yi;
  float vp = si * xi - ci * yi;
  p[10] = up;
  p[11] = vp;
  upv[i] = up;        // contiguous copies for coalesced init-reduction
  upv[NN + i] = vp;
}

__global__ __launch_bounds__(64) void scan_kernel(const float* __restrict__ st,
                                                  const float* __restrict__ upv,
                                                  const float* __restrict__ amp,
                                                  const float* __restrict__ bvec,
                                                  float* __restrict__ out) {
  __shared__ float lds[CHUNK * 12];  // 48 KB
  const int lane = threadIdx.x;

  // ---- initial U, V over original state (deterministic wave reduction) ----
  float u = 0.f, v = 0.f;
#pragma unroll
  for (int k = 0; k < NN / 64; ++k) {
    u += upv[k * 64 + lane];
    v += upv[NN + k * 64 + lane];
  }
#pragma unroll
  for (int off = 32; off; off >>= 1) {
    u += __shfl_xor(u, off, 64);
    v += __shfl_xor(v, off, 64);
  }
  float U = u, V = v;  // identical in all lanes
  float ykeep = 0.f;

  for (int c = 0; c < NN / CHUNK; ++c) {
    __syncthreads();
    // stage this chunk's structs into LDS (coalesced float4 copy)
    const float4* src = reinterpret_cast<const float4*>(st + c * CHUNK * 12);
    float4* dst = reinterpret_cast<float4*>(lds);
    for (int t = lane; t < CHUNK * 12 / 4; t += 64) dst[t] = src[t];
    __syncthreads();

    for (int g = 0; g < CHUNK; g += 64) {
#pragma unroll 8
      for (int i = g; i < g + 64; ++i) {
        const float4 a  = *reinterpret_cast<const float4*>(&lds[i * 12]);
        const float4 bq = *reinterpret_cast<const float4*>(&lds[i * 12 + 4]);
        const float4 cq = *reinterpret_cast<const float4*>(&lds[i * 12 + 8]);
        float ci = a.x, si = a.y;
        // xd = ci*U + si*V + axx ; yd = si*U - ci*V + ayy
        float xd = fmaf(ci, U, fmaf(si, V, a.z));
        float yd = fmaf(si, U, fmaf(-ci, V, a.w));
        // clip commuted through the affine map x_new = xi + clamp(xd)*DT
        float xn = fminf(fmaxf(fmaf(xd, DT, bq.x), bq.z), bq.w);
        float yn = fminf(fmaxf(fmaf(yd, DT, bq.y), cq.x), cq.y);
        // running-sum update: U += ci*(xn-xi) + si*(yn-yi)  (folded via up/vp)
        float tU = U - cq.z;
        float tV = V - cq.w;
        U = fmaf(ci, xn, fmaf(si, yn, tU));
        V = fmaf(si, xn, fmaf(-ci, yn, tV));
        // lane (i&63) keeps this step's y_new for the coalesced flush
        ykeep = ((i & 63) == lane) ? yn : ykeep;
      }
      int base = c * CHUNK + g;
      float am = amp[base + lane];
      float bb = bvec[base + lane];
      float ang = fmaf(am, ykeep, bb);
      out[base + lane] = fminf(fmaxf(ang, -HB), HB);
    }
  }
}

extern "C" void kernel_launch(void* const* d_in, const int* in_sizes, int n_in,
                              void* d_out, int out_size, void* d_ws, size_t ws_size,
                              hipStream_t stream) {
  const float* phase = (const float*)d_in[0];
  const float* amp   = (const float*)d_in[1];
  const float* w     = (const float*)d_in[2];
  const float* ha    = (const float*)d_in[3];
  const float* b     = (const float*)d_in[4];
  const float* xy    = (const float*)d_in[5];
  const float* xydo  = (const float*)d_in[6];
  float* out = (float*)d_out;

  float* st  = (float*)d_ws;       // NN*12 floats
  float* upv = st + NN * 12;       // 2*NN floats

  prep_kernel<<<NN / 256, 256, 0, stream>>>(phase, w, ha, xy, xydo, st, upv);
  scan_kernel<<<1, 64, 0, stream>>>(st, upv, amp, b, out);
}

// Round 2
// 303.544 us; speedup vs baseline: 1.0333x; 1.0333x over previous
//
#include <hip/hip_runtime.h>
#include <math.h>

#define NN 4096
#define ALPHA 0.1f
#define DT 0.01f
#define DIFF 10.0f
#define EPS 1e-9f
#define HB 1.5707963267948966f
#define CHUNK 1024              // steps per LDS refill
#define NCHUNK (NN / CHUNK)
#define NGRP (CHUNK / 4)        // 4-step groups per chunk

// Per-step constants, 8 floats (2x float4), laid out linearly in LDS:
//  q0 = (ci, si, axx, ayy)   q1 = (xlo, xhi, ylo, yhi)
// Scan recurrence (all lanes redundant, wave-uniform):
//  xd = ci*U + si*V + axx ; yd = si*U - ci*V + ayy
//  cx = clamp(xd, xlo, xhi) ; cy = clamp(yd, ylo, yhi)
//  dx = DT*cx ; dy = DT*cy
//  U += ci*dx + si*dy ; V += si*dx - ci*dy
//  y_new_i = yi + dy  (only owning lane keeps dy; yi folded in at flush)

#define LOADG(P, gidx) do {                                   \
    const float4* _q = ((const float4*)st) + (gidx) * 8;      \
    P##0 = _q[0]; P##1 = _q[1]; P##2 = _q[2]; P##3 = _q[3];   \
    P##4 = _q[4]; P##5 = _q[5]; P##6 = _q[6]; P##7 = _q[7];   \
  } while (0)

#define STEP(q0, q1, sidx) do {                               \
    float xd = fmaf(q0.x, U, fmaf(q0.y, V, q0.z));            \
    float yd = fmaf(q0.y, U, fmaf(-q0.x, V, q0.w));           \
    float cx = fminf(fmaxf(xd, q1.x), q1.y);                  \
    float cy = fminf(fmaxf(yd, q1.z), q1.w);                  \
    float dx = cx * DT;                                       \
    float dy = cy * DT;                                       \
    U = fmaf(q0.x, dx, fmaf(q0.y, dy, U));                    \
    V = fmaf(q0.y, dx, fmaf(-q0.x, dy, V));                   \
    dyk = (((sidx) & 63) == lane) ? dy : dyk;                 \
  } while (0)

__global__ __launch_bounds__(64) void cpg_kernel(
    const float* __restrict__ phase, const float* __restrict__ amp,
    const float* __restrict__ w, const float* __restrict__ ha,
    const float* __restrict__ bvec, const float* __restrict__ xy,
    const float* __restrict__ xydo, float* __restrict__ out) {
  __shared__ float st[CHUNK * 8];  // 32 KB, one chunk of step-constants
  const int lane = threadIdx.x;
  const float2* xy2 = (const float2*)xy;
  const float2* xd2 = (const float2*)xydo;

  // ---- initial U = sum(cj*xj + sj*yj), V = sum(sj*xj - cj*yj) ----
  float u = 0.f, v = 0.f;
#pragma unroll 4
  for (int it = 0; it < NN / 64; ++it) {
    int i = it * 64 + lane;
    float ph = phase[i];
    float ci = cosf(ph), si = sinf(ph);
    float2 p = xy2[i];
    u = fmaf(ci, p.x, fmaf(si, p.y, u));
    v = fmaf(si, p.x, fmaf(-ci, p.y, v));
  }
#pragma unroll
  for (int off = 32; off; off >>= 1) {
    u += __shfl_xor(u, off, 64);
    v += __shfl_xor(v, off, 64);
  }
  float U = u, V = v;  // identical across lanes
  float dyk = 0.f;

  for (int c = 0; c < NCHUNK; ++c) {
    __syncthreads();
    // ---- prep chunk c: fold all per-step constants into LDS ----
#pragma unroll 2
    for (int it = 0; it < CHUNK / 64; ++it) {
      int s = it * 64 + lane;
      int i = c * CHUNK + s;
      float ph = phase[i];
      float ci = cosf(ph), si = sinf(ph);
      float2 p = xy2[i];
      float2 d = xd2[i];
      float r2 = fmaf(p.x, p.x, p.y * p.y);
      float ta = ALPHA * (1.f - r2 * r2);
      float zeta = 1.f - ha[i] * ((d.x + EPS) / (fabsf(d.x) + EPS));
      float tb = w[i] / (zeta + EPS);
      float4 q0 = make_float4(ci, si,
                              ta * p.x - tb * p.y - p.x,
                              tb * p.x + ta * p.y - p.y);
      float4 q1 = make_float4(d.x - DIFF, d.x + DIFF, d.y - DIFF, d.y + DIFF);
      ((float4*)st)[s * 2 + 0] = q0;
      ((float4*)st)[s * 2 + 1] = q1;
    }
    __syncthreads();

    // ---- scan this chunk: 4-step groups, A/B register ping-pong ----
    float4 A0, A1, A2, A3, A4, A5, A6, A7;
    float4 B0, B1, B2, B3, B4, B5, B6, B7;
    LOADG(A, 0);

    for (int blk = 0; blk < CHUNK / 64; ++blk) {
      int gb = c * CHUNK + blk * 64 + lane;
      float a_ = amp[gb];
      float bb = bvec[gb];
      float yi = xy2[gb].y;

      for (int gp = 0; gp < 8; ++gp) {
        int g = blk * 16 + gp * 2;          // even group
        LOADG(B, g + 1);                    // prefetch odd group
        STEP(A0, A1, g * 4 + 0);
        STEP(A2, A3, g * 4 + 1);
        STEP(A4, A5, g * 4 + 2);
        STEP(A6, A7, g * 4 + 3);
        LOADG(A, (g + 2) & (NGRP - 1));     // prefetch next even (wraps, harmless)
        STEP(B0, B1, g * 4 + 4);
        STEP(B2, B3, g * 4 + 5);
        STEP(B4, B5, g * 4 + 6);
        STEP(B6, B7, g * 4 + 7);
      }
      // flush this 64-step block (coalesced, fused epilogue)
      float ang = fmaf(a_, yi + dyk, bb);
      out[gb] = fminf(fmaxf(ang, -HB), HB);
    }
  }
}

extern "C" void kernel_launch(void* const* d_in, const int* in_sizes, int n_in,
                              void* d_out, int out_size, void* d_ws, size_t ws_size,
                              hipStream_t stream) {
  const float* phase = (const float*)d_in[0];
  const float* amp   = (const float*)d_in[1];
  const float* w     = (const float*)d_in[2];
  const float* ha    = (const float*)d_in[3];
  const float* b     = (const float*)d_in[4];
  const float* xy    = (const float*)d_in[5];
  const float* xydo  = (const float*)d_in[6];
  float* out = (float*)d_out;

  cpg_kernel<<<1, 64, 0, stream>>>(phase, amp, w, ha, b, xy, xydo, out);
}